// Round 1
// baseline (226.249 us; speedup 1.0000x reference)
//
#include <hip/hip_runtime.h>

typedef __bf16 bf16_t;
typedef __bf16 bf16x8 __attribute__((ext_vector_type(8)));
typedef float f32x4 __attribute__((ext_vector_type(4)));

#define BM 128
#define BN 128
#define BK 32

// N_NODES=24576, F=512, M_TOT=15, degrees 1,2,3 -> segments [0,3),[3,8),[8,15)
// ws layout (bytes):
//   0        W1b   (512*512 bf16)  = 524288
//   524288   W2t   (512*512 bf16)  = 524288
//   1048576  W4t   (512*1536 bf16) = 1572864
//   2621440  Wct   (512*512 bf16)  = 524288
//   3145728  bc    (512 f32)       = 2048
//   3147776  u     (512 f32)       = 2048
//   3149824  Xb / A3 (overlapped; max = 24576*1536*2 = 75497472)
// total ~78.7 MB

__device__ __forceinline__ void g2l16(const void* g, void* l) {
    __builtin_amdgcn_global_load_lds((__attribute__((address_space(1))) void*)(g),
                                     (__attribute__((address_space(3))) void*)(l),
                                     16, 0, 0);
}

// C[m][n] = sum_k A[m][k] * Bt[n][k]  (+ bias[n])
// mode 0: store bf16; mode 1: store f32 silu(v)
__global__ __launch_bounds__(256)
void gemm_bt_kernel(const bf16_t* __restrict__ A, const bf16_t* __restrict__ Bt,
                    const float* __restrict__ bias, void* __restrict__ Cout,
                    int N, int K, int mode)
{
    __shared__ __align__(16) bf16_t lA[BM * BK];
    __shared__ __align__(16) bf16_t lB[BN * BK];

    const int tid  = threadIdx.x;
    const int lane = tid & 63;
    const int wave = tid >> 6;
    const int wr   = wave >> 1;      // 0..1
    const int wc   = wave & 1;       // 0..1
    const int col0 = lane & 15;
    const int kh   = lane >> 4;      // 0..3

    const int bm = blockIdx.x;
    const int bn = blockIdx.y;

    // staging: flat byte o = (tid + i*256)*16 ; row = o/64, byte-in-row = o%64
    const int rs = tid >> 2;                 // 0..63 (+64 for second chunk)
    const int cb = (tid & 3) * 16;

    const size_t strb = (size_t)K * 2;       // row stride in bytes (both A and Bt)
    const char* gA = (const char*)A  + ((size_t)bm * BM + rs) * strb + cb;
    const char* gB = (const char*)Bt + ((size_t)bn * BN + rs) * strb + cb;

    char* lAb = (char*)lA + tid * 16;
    char* lBb = (char*)lB + tid * 16;

    f32x4 acc[4][4] = {};

    const bf16x8* pa = (const bf16x8*)(lA + (wr * 64 + col0) * BK + kh * 8);
    const bf16x8* pb = (const bf16x8*)(lB + (wc * 64 + col0) * BK + kh * 8);

    const int nk = K / BK;
    for (int kt = 0; kt < nk; ++kt) {
        const size_t kb = (size_t)kt * (BK * 2);
        g2l16(gA + kb,             lAb);
        g2l16(gA + 64 * strb + kb, lAb + 4096);
        g2l16(gB + kb,             lBb);
        g2l16(gB + 64 * strb + kb, lBb + 4096);
        __syncthreads();   // compiler emits vmcnt(0) drain before barrier

        bf16x8 av[4], bw[4];
#pragma unroll
        for (int i = 0; i < 4; ++i) {
            av[i] = pa[i * 64];   // +16 rows = 512 elems = 64 vectors
            bw[i] = pb[i * 64];
        }
#pragma unroll
        for (int mi = 0; mi < 4; ++mi)
#pragma unroll
            for (int ni = 0; ni < 4; ++ni)
                acc[mi][ni] = __builtin_amdgcn_mfma_f32_16x16x32_bf16(
                    av[mi], bw[ni], acc[mi][ni], 0, 0, 0);
        __syncthreads();
    }

    // C/D frag layout: col = lane&15, row = (lane>>4)*4 + j   [guide-verified]
    const int gr0 = bm * BM + wr * 64 + kh * 4;
    const int gc0 = bn * BN + wc * 64 + col0;
    if (mode == 0) {
        bf16_t* C = (bf16_t*)Cout;
#pragma unroll
        for (int mi = 0; mi < 4; ++mi)
#pragma unroll
            for (int ni = 0; ni < 4; ++ni) {
                const int c = gc0 + ni * 16;
                const float bv = bias ? bias[c] : 0.f;
#pragma unroll
                for (int j = 0; j < 4; ++j) {
                    const int r = gr0 + mi * 16 + j;
                    C[(size_t)r * N + c] = (bf16_t)(acc[mi][ni][j] + bv);
                }
            }
    } else {
        float* C = (float*)Cout;
#pragma unroll
        for (int mi = 0; mi < 4; ++mi)
#pragma unroll
            for (int ni = 0; ni < 4; ++ni) {
                const int c = gc0 + ni * 16;
                const float bv = bias[c];
#pragma unroll
                for (int j = 0; j < 4; ++j) {
                    const int r = gr0 + mi * 16 + j;
                    float v = acc[mi][ni][j] + bv;
                    C[(size_t)r * N + c] = v / (1.f + __expf(-v));
                }
            }
    }
}

__global__ void cast8_kernel(const float* __restrict__ in, bf16_t* __restrict__ out, int n8) {
    const int i = blockIdx.x * blockDim.x + threadIdx.x;
    if (i >= n8) return;
    const float4* p = (const float4*)in + (size_t)i * 2;
    float4 a = p[0], b = p[1];
    bf16x8 v;
    v[0] = (bf16_t)a.x; v[1] = (bf16_t)a.y; v[2] = (bf16_t)a.z; v[3] = (bf16_t)a.w;
    v[4] = (bf16_t)b.x; v[5] = (bf16_t)b.y; v[6] = (bf16_t)b.z; v[7] = (bf16_t)b.w;
    *(bf16x8*)(out + (size_t)i * 8) = v;
}

// out[c*R + r] = in[r*C + c]   (in: R x C, out: C x R), cast to bf16
__global__ void transpose_cast_kernel(const float* __restrict__ in, bf16_t* __restrict__ out,
                                      int R, int C) {
    const int idx = blockIdx.x * blockDim.x + threadIdx.x;
    if (idx >= R * C) return;
    const int c = idx / R;
    const int r = idx - c * R;
    out[idx] = (bf16_t)in[(size_t)r * C + c];
}

// u[t] = sum_i b1[i] * W1[i][t]
__global__ void vecmat_kernel(const float* __restrict__ v, const float* __restrict__ W,
                              float* __restrict__ out) {
    const int t = blockIdx.x * blockDim.x + threadIdx.x;
    if (t >= 512) return;
    float s = 0.f;
    for (int i = 0; i < 512; ++i) s += v[i] * W[i * 512 + t];
    out[t] = s;
}

// per node: s = g.W3 ; chi_bo = chi*s ; A3[n, l*512+f] = c_l * g[f]^2
__global__ __launch_bounds__(256)
void mid_kernel(const bf16_t* __restrict__ G, const float* __restrict__ chi,
                const float* __restrict__ W3, float* __restrict__ chbo,
                bf16_t* __restrict__ A3)
{
    const int node = blockIdx.x * 4 + (threadIdx.x >> 6);
    const int lane = threadIdx.x & 63;

    const bf16x8 gv = *(const bf16x8*)(G + (size_t)node * 512 + lane * 8);
    float g[8];
#pragma unroll
    for (int j = 0; j < 8; ++j) g[j] = (float)gv[j];

    float s = 0.f;
    const float* w = W3 + lane * 8;
#pragma unroll
    for (int j = 0; j < 8; ++j) s += g[j] * w[j];
#pragma unroll
    for (int off = 32; off > 0; off >>= 1) s += __shfl_xor(s, off, 64);

    const float* ch = chi + (size_t)node * 15;
    float c0 = 0.f, c1 = 0.f, c2 = 0.f;
#pragma unroll
    for (int m = 0; m < 3; ++m)  c0 += ch[m] * ch[m];
#pragma unroll
    for (int m = 3; m < 8; ++m)  c1 += ch[m] * ch[m];
#pragma unroll
    for (int m = 8; m < 15; ++m) c2 += ch[m] * ch[m];

    if (lane < 15) chbo[(size_t)node * 15 + lane] = ch[lane] * s;

    const float cl[3] = {c0, c1, c2};
    bf16_t* arow = A3 + (size_t)node * 1536 + lane * 8;
#pragma unroll
    for (int l = 0; l < 3; ++l) {
        bf16x8 o;
#pragma unroll
        for (int j = 0; j < 8; ++j) o[j] = (bf16_t)(cl[l] * g[j] * g[j]);
        *(bf16x8*)(arow + l * 512) = o;
    }
}

extern "C" void kernel_launch(void* const* d_in, const int* in_sizes, int n_in,
                              void* d_out, int out_size, void* d_ws, size_t ws_size,
                              hipStream_t stream)
{
    const float* x   = (const float*)d_in[0];
    const float* chi = (const float*)d_in[1];
    // d_in[2] = z_one_hot : unused by the reference computation
    const float* W1  = (const float*)d_in[3];
    const float* b1  = (const float*)d_in[4];
    const float* W2  = (const float*)d_in[5];
    const float* W3  = (const float*)d_in[6];
    const float* W4  = (const float*)d_in[7];
    const float* b4  = (const float*)d_in[8];

    char* ws = (char*)d_ws;
    bf16_t* W1b = (bf16_t*)(ws + 0);
    bf16_t* W2t = (bf16_t*)(ws + 524288);
    bf16_t* W4t = (bf16_t*)(ws + 1048576);
    bf16_t* Wct = (bf16_t*)(ws + 2621440);
    float*  bc  = (float*) (ws + 3145728);
    float*  u   = (float*) (ws + 3147776);
    bf16_t* Xb  = (bf16_t*)(ws + 3149824);
    bf16_t* A3  = (bf16_t*)(ws + 3149824);   // overlaps Xb (dead by then)

    float*  xbo  = (float*)d_out;                                // 24576*512 f32
    float*  chbo = (float*)d_out + (size_t)24576 * 512;          // 24576*15 f32
    bf16_t* Gb   = (bf16_t*)d_out;   // bf16 scratch inside chunk0 (dead before final GEMM)

    // prep: casts / transposes / fused bias  bc = (b1 @ W1) @ W2
    cast8_kernel<<<6144, 256, 0, stream>>>(x, Xb, 1572864);
    cast8_kernel<<<128, 256, 0, stream>>>(W1, W1b, 32768);
    transpose_cast_kernel<<<1024, 256, 0, stream>>>(W2, W2t, 512, 512);
    transpose_cast_kernel<<<3072, 256, 0, stream>>>(W4, W4t, 1536, 512);
    vecmat_kernel<<<2, 256, 0, stream>>>(b1, W1, u);
    vecmat_kernel<<<2, 256, 0, stream>>>(u, W2, bc);

    // Wct = (W1@W2)^T = W2^T @ W1^T :  C[j][i] = sum_t W2t[j][t] * W1[i][t]
    gemm_bt_kernel<<<dim3(4, 4), 256, 0, stream>>>(W2t, W1b, nullptr, Wct, 512, 512, 0);

    // G = x @ (W1@W2) + bc : C[n][j] = sum_k Xb[n][k] * Wct[j][k] + bc[j]  -> bf16
    gemm_bt_kernel<<<dim3(192, 4), 256, 0, stream>>>(Xb, Wct, bc, Gb, 512, 512, 0);

    // s, chi_bo, A3
    mid_kernel<<<6144, 256, 0, stream>>>(Gb, chi, W3, chbo, A3);

    // x_bo = silu(A3 @ W4 + b4) : C[n][j] = sum_k A3[n][k] * W4t[j][k]
    gemm_bt_kernel<<<dim3(192, 4), 256, 0, stream>>>(A3, W4t, b4, xbo, 512, 1536, 1);
}

// Round 2
// 223.639 us; speedup vs baseline: 1.0117x; 1.0117x over previous
//
#include <hip/hip_runtime.h>

typedef __bf16 bf16_t;
typedef __bf16 bf16x8 __attribute__((ext_vector_type(8)));
typedef float f32x4 __attribute__((ext_vector_type(4)));

#define BM 128
#define BN 128
#define BK 32

// N_NODES=24576, F=512, M_TOT=15, degrees 1,2,3 -> segments [0,3),[3,8),[8,15)
// ws layout (bytes):
//   0        W1b   (512*512 bf16)  = 524288
//   524288   W2t   (512*512 bf16)  = 524288
//   1048576  W4t   (512*1536 bf16) = 1572864
//   2621440  Wct   (512*512 bf16)  = 524288
//   3145728  bc    (512 f32)       = 2048
//   3147776  u     (512 f32)       = 2048
//   3149824  Xb / A3 (overlapped; max = 24576*1536*2 = 75497472)

__device__ __forceinline__ void g2l16(const void* g, void* l) {
    __builtin_amdgcn_global_load_lds((__attribute__((address_space(1))) void*)(g),
                                     (__attribute__((address_space(3))) void*)(l),
                                     16, 0, 0);
}

// C[m][n] = sum_k A[m][k] * Bt[n][k]  (+ bias[n])
// mode 0: store bf16; mode 1: store f32 silu(v)
// 2-phase double-buffered pipeline (T3-minimum): stage(t+1) issued BEFORE
// compute(t); single barrier per K-step drains the in-flight loads after
// compute has covered their latency.
__global__ __launch_bounds__(256)
void gemm_bt_kernel(const bf16_t* __restrict__ A, const bf16_t* __restrict__ Bt,
                    const float* __restrict__ bias, void* __restrict__ Cout,
                    int N, int K, int mode)
{
    __shared__ __align__(16) bf16_t lA[2][BM * BK];   // 8 KB each
    __shared__ __align__(16) bf16_t lB[2][BN * BK];

    const int tid  = threadIdx.x;
    const int lane = tid & 63;
    const int wave = tid >> 6;
    const int wr   = wave >> 1;      // 0..1
    const int wc   = wave & 1;       // 0..1
    const int col0 = lane & 15;
    const int kh   = lane >> 4;      // 0..3

    const int bm = blockIdx.x;
    const int bn = blockIdx.y;

    // staging: flat byte o = tid*16 (+4096 for second chunk); row = o/64
    const int rs = tid >> 2;                 // 0..63 (+64 for second chunk)
    const int cb = (tid & 3) * 16;

    const size_t strb = (size_t)K * 2;       // row stride in bytes (both A and Bt)
    const char* gA = (const char*)A  + ((size_t)bm * BM + rs) * strb + cb;
    const char* gB = (const char*)Bt + ((size_t)bn * BN + rs) * strb + cb;

    f32x4 acc[4][4] = {};

    auto stage = [&](int kt, int buf) {
        const size_t kb = (size_t)kt * (BK * 2);
        char* la = (char*)&lA[buf][0] + tid * 16;
        char* lb = (char*)&lB[buf][0] + tid * 16;
        g2l16(gA + kb,             la);
        g2l16(gA + 64 * strb + kb, la + 4096);
        g2l16(gB + kb,             lb);
        g2l16(gB + 64 * strb + kb, lb + 4096);
    };

    auto compute = [&](int buf) {
        const bf16x8* pa = (const bf16x8*)(&lA[buf][0] + (wr * 64 + col0) * BK + kh * 8);
        const bf16x8* pb = (const bf16x8*)(&lB[buf][0] + (wc * 64 + col0) * BK + kh * 8);
        bf16x8 av[4], bw[4];
#pragma unroll
        for (int i = 0; i < 4; ++i) {
            av[i] = pa[i * 64];   // +16 rows = 512 elems = 64 vectors
            bw[i] = pb[i * 64];
        }
#pragma unroll
        for (int mi = 0; mi < 4; ++mi)
#pragma unroll
            for (int ni = 0; ni < 4; ++ni)
                acc[mi][ni] = __builtin_amdgcn_mfma_f32_16x16x32_bf16(
                    av[mi], bw[ni], acc[mi][ni], 0, 0, 0);
    };

    const int nk = K / BK;
    stage(0, 0);
    __syncthreads();          // drain prologue loads (vmcnt(0)) + sync

    int cur = 0;
    for (int kt = 0; kt < nk - 1; ++kt) {
        stage(kt + 1, cur ^ 1);   // issue next-tile loads first (overlap w/ compute)
        compute(cur);
        __syncthreads();          // single per-iter barrier: drains this iter's loads
        cur ^= 1;
    }
    compute(cur);                 // last tile: nothing in flight

    // C/D frag layout: col = lane&15, row = (lane>>4)*4 + j   [guide-verified]
    const int gr0 = bm * BM + wr * 64 + kh * 4;
    const int gc0 = bn * BN + wc * 64 + col0;
    if (mode == 0) {
        bf16_t* C = (bf16_t*)Cout;
#pragma unroll
        for (int mi = 0; mi < 4; ++mi)
#pragma unroll
            for (int ni = 0; ni < 4; ++ni) {
                const int c = gc0 + ni * 16;
                const float bv = bias ? bias[c] : 0.f;
#pragma unroll
                for (int j = 0; j < 4; ++j) {
                    const int r = gr0 + mi * 16 + j;
                    C[(size_t)r * N + c] = (bf16_t)(acc[mi][ni][j] + bv);
                }
            }
    } else {
        float* C = (float*)Cout;
#pragma unroll
        for (int mi = 0; mi < 4; ++mi)
#pragma unroll
            for (int ni = 0; ni < 4; ++ni) {
                const int c = gc0 + ni * 16;
                const float bv = bias[c];
#pragma unroll
                for (int j = 0; j < 4; ++j) {
                    const int r = gr0 + mi * 16 + j;
                    float v = acc[mi][ni][j] + bv;
                    C[(size_t)r * N + c] = v / (1.f + __expf(-v));
                }
            }
    }
}

__global__ void cast8_kernel(const float* __restrict__ in, bf16_t* __restrict__ out, int n8) {
    const int i = blockIdx.x * blockDim.x + threadIdx.x;
    if (i >= n8) return;
    const float4* p = (const float4*)in + (size_t)i * 2;
    float4 a = p[0], b = p[1];
    bf16x8 v;
    v[0] = (bf16_t)a.x; v[1] = (bf16_t)a.y; v[2] = (bf16_t)a.z; v[3] = (bf16_t)a.w;
    v[4] = (bf16_t)b.x; v[5] = (bf16_t)b.y; v[6] = (bf16_t)b.z; v[7] = (bf16_t)b.w;
    *(bf16x8*)(out + (size_t)i * 8) = v;
}

// out[c*R + r] = in[r*C + c]   (in: R x C, out: C x R), cast to bf16
__global__ void transpose_cast_kernel(const float* __restrict__ in, bf16_t* __restrict__ out,
                                      int R, int C) {
    const int idx = blockIdx.x * blockDim.x + threadIdx.x;
    if (idx >= R * C) return;
    const int c = idx / R;
    const int r = idx - c * R;
    out[idx] = (bf16_t)in[(size_t)r * C + c];
}

// u[t] = sum_i v[i] * W[i][t]
__global__ void vecmat_kernel(const float* __restrict__ v, const float* __restrict__ W,
                              float* __restrict__ out) {
    const int t = blockIdx.x * blockDim.x + threadIdx.x;
    if (t >= 512) return;
    float s = 0.f;
    for (int i = 0; i < 512; ++i) s += v[i] * W[i * 512 + t];
    out[t] = s;
}

// per node: s = g.W3 ; chi_bo = chi*s ; A3[n, l*512+f] = c_l * g[f]^2
__global__ __launch_bounds__(256)
void mid_kernel(const bf16_t* __restrict__ G, const float* __restrict__ chi,
                const float* __restrict__ W3, float* __restrict__ chbo,
                bf16_t* __restrict__ A3)
{
    const int node = blockIdx.x * 4 + (threadIdx.x >> 6);
    const int lane = threadIdx.x & 63;

    const bf16x8 gv = *(const bf16x8*)(G + (size_t)node * 512 + lane * 8);
    float g[8];
#pragma unroll
    for (int j = 0; j < 8; ++j) g[j] = (float)gv[j];

    float s = 0.f;
    const float* w = W3 + lane * 8;
#pragma unroll
    for (int j = 0; j < 8; ++j) s += g[j] * w[j];
#pragma unroll
    for (int off = 32; off > 0; off >>= 1) s += __shfl_xor(s, off, 64);

    const float* ch = chi + (size_t)node * 15;
    float c0 = 0.f, c1 = 0.f, c2 = 0.f;
#pragma unroll
    for (int m = 0; m < 3; ++m)  c0 += ch[m] * ch[m];
#pragma unroll
    for (int m = 3; m < 8; ++m)  c1 += ch[m] * ch[m];
#pragma unroll
    for (int m = 8; m < 15; ++m) c2 += ch[m] * ch[m];

    if (lane < 15) chbo[(size_t)node * 15 + lane] = ch[lane] * s;

    const float cl[3] = {c0, c1, c2};
    bf16_t* arow = A3 + (size_t)node * 1536 + lane * 8;
#pragma unroll
    for (int l = 0; l < 3; ++l) {
        bf16x8 o;
#pragma unroll
        for (int j = 0; j < 8; ++j) o[j] = (bf16_t)(cl[l] * g[j] * g[j]);
        *(bf16x8*)(arow + l * 512) = o;
    }
}

extern "C" void kernel_launch(void* const* d_in, const int* in_sizes, int n_in,
                              void* d_out, int out_size, void* d_ws, size_t ws_size,
                              hipStream_t stream)
{
    const float* x   = (const float*)d_in[0];
    const float* chi = (const float*)d_in[1];
    // d_in[2] = z_one_hot : unused by the reference computation
    const float* W1  = (const float*)d_in[3];
    const float* b1  = (const float*)d_in[4];
    const float* W2  = (const float*)d_in[5];
    const float* W3  = (const float*)d_in[6];
    const float* W4  = (const float*)d_in[7];
    const float* b4  = (const float*)d_in[8];

    char* ws = (char*)d_ws;
    bf16_t* W1b = (bf16_t*)(ws + 0);
    bf16_t* W2t = (bf16_t*)(ws + 524288);
    bf16_t* W4t = (bf16_t*)(ws + 1048576);
    bf16_t* Wct = (bf16_t*)(ws + 2621440);
    float*  bc  = (float*) (ws + 3145728);
    float*  u   = (float*) (ws + 3147776);
    bf16_t* Xb  = (bf16_t*)(ws + 3149824);
    bf16_t* A3  = (bf16_t*)(ws + 3149824);   // overlaps Xb (dead by then)

    float*  xbo  = (float*)d_out;                                // 24576*512 f32
    float*  chbo = (float*)d_out + (size_t)24576 * 512;          // 24576*15 f32
    bf16_t* Gb   = (bf16_t*)d_out;   // bf16 scratch inside chunk0 (dead before final GEMM)

    // prep: casts / transposes / fused bias  bc = (b1 @ W1) @ W2
    cast8_kernel<<<6144, 256, 0, stream>>>(x, Xb, 1572864);
    cast8_kernel<<<128, 256, 0, stream>>>(W1, W1b, 32768);
    transpose_cast_kernel<<<1024, 256, 0, stream>>>(W2, W2t, 512, 512);
    transpose_cast_kernel<<<3072, 256, 0, stream>>>(W4, W4t, 1536, 512);
    vecmat_kernel<<<2, 256, 0, stream>>>(b1, W1, u);
    vecmat_kernel<<<2, 256, 0, stream>>>(u, W2, bc);

    // Wct = (W1@W2)^T = W2^T @ W1^T :  C[j][i] = sum_t W2t[j][t] * W1[i][t]
    gemm_bt_kernel<<<dim3(4, 4), 256, 0, stream>>>(W2t, W1b, nullptr, Wct, 512, 512, 0);

    // G = x @ (W1@W2) + bc : C[n][j] = sum_k Xb[n][k] * Wct[j][k] + bc[j]  -> bf16
    gemm_bt_kernel<<<dim3(192, 4), 256, 0, stream>>>(Xb, Wct, bc, Gb, 512, 512, 0);

    // s, chi_bo, A3
    mid_kernel<<<6144, 256, 0, stream>>>(Gb, chi, W3, chbo, A3);

    // x_bo = silu(A3 @ W4 + b4) : C[n][j] = sum_k A3[n][k] * W4t[j][k]
    gemm_bt_kernel<<<dim3(192, 4), 256, 0, stream>>>(A3, W4t, b4, xbo, 512, 1536, 1);
}

// Round 3
// 216.967 us; speedup vs baseline: 1.0428x; 1.0308x over previous
//
#include <hip/hip_runtime.h>

typedef __bf16 bf16_t;
typedef __bf16 bf16x8 __attribute__((ext_vector_type(8)));
typedef float f32x4 __attribute__((ext_vector_type(4)));

#define BM 128
#define BN 128
#define BK 32

// N_NODES=24576, F=512, M_TOT=15, degrees 1,2,3 -> segments [0,3),[3,8),[8,15)
// ws layout (bytes):
//   0        W1b   (512*512 bf16)  = 524288
//   524288   W2t   (512*512 bf16)  = 524288
//   1048576  W4t   (512*1536 bf16) = 1572864
//   2621440  Wct   (512*512 bf16)  = 524288
//   3145728  bc    (512 f32)       = 2048
//   3147776  u     (512 f32)       = 2048
//   3149824  Xb / A3 (overlapped; max = 24576*1536*2 = 75497472)

__device__ __forceinline__ void g2l16(const void* g, void* l) {
    __builtin_amdgcn_global_load_lds((__attribute__((address_space(1))) void*)(g),
                                     (__attribute__((address_space(3))) void*)(l),
                                     16, 0, 0);
}

// C[m][n] = sum_k A[m][k] * Bt[n][k]  (+ bias[n])
// mode 0: store bf16; mode 1: store f32 silu(v)
// 3-stage pipeline (T3+T4): prefetch 2 K-tiles ahead via global_load_lds,
// RAW s_barrier + counted vmcnt (never vmcnt(0) in steady state) so loads
// stay in flight across barriers. sched_barrier(0) fences pin the order.
__global__ __launch_bounds__(256)
void gemm_bt_kernel(const bf16_t* __restrict__ A, const bf16_t* __restrict__ Bt,
                    const float* __restrict__ bias, void* __restrict__ Cout,
                    int N, int K, int mode)
{
    __shared__ __align__(16) bf16_t lA[3][BM * BK];   // 8 KB each
    __shared__ __align__(16) bf16_t lB[3][BN * BK];

    const int tid  = threadIdx.x;
    const int lane = tid & 63;
    const int wave = tid >> 6;
    const int wr   = wave >> 1;      // 0..1
    const int wc   = wave & 1;       // 0..1
    const int col0 = lane & 15;
    const int kh   = lane >> 4;      // 0..3

    const int bm = blockIdx.x;
    const int bn = blockIdx.y;

    // staging: flat byte o = tid*16 (+4096 for second chunk); row = o/64
    const int rs = tid >> 2;                 // 0..63 (+64 for second chunk)
    const int cb = (tid & 3) * 16;

    const size_t strb = (size_t)K * 2;       // row stride in bytes (both A and Bt)
    const char* gA = (const char*)A  + ((size_t)bm * BM + rs) * strb + cb;
    const char* gB = (const char*)Bt + ((size_t)bn * BN + rs) * strb + cb;

    f32x4 acc[4][4] = {};

    auto stage = [&](int kt, int buf) {
        const size_t kb = (size_t)kt * (BK * 2);
        char* la = (char*)&lA[buf][0] + tid * 16;
        char* lb = (char*)&lB[buf][0] + tid * 16;
        g2l16(gA + kb,             la);
        g2l16(gA + 64 * strb + kb, la + 4096);
        g2l16(gB + kb,             lb);
        g2l16(gB + 64 * strb + kb, lb + 4096);
    };

    auto compute = [&](int buf) {
        const bf16x8* pa = (const bf16x8*)(&lA[buf][0] + (wr * 64 + col0) * BK + kh * 8);
        const bf16x8* pb = (const bf16x8*)(&lB[buf][0] + (wc * 64 + col0) * BK + kh * 8);
        bf16x8 av[4], bw[4];
#pragma unroll
        for (int i = 0; i < 4; ++i) {
            av[i] = pa[i * 64];   // +16 rows = 512 elems = 64 vectors
            bw[i] = pb[i * 64];
        }
#pragma unroll
        for (int mi = 0; mi < 4; ++mi)
#pragma unroll
            for (int ni = 0; ni < 4; ++ni)
                acc[mi][ni] = __builtin_amdgcn_mfma_f32_16x16x32_bf16(
                    av[mi], bw[ni], acc[mi][ni], 0, 0, 0);
    };

    const int nk = K / BK;       // >= 16 for all our shapes
    stage(0, 0);
    stage(1, 1);                 // 8 loads in flight; no barrier yet

    for (int kt = 0; kt < nk; ++kt) {
        if (kt + 2 < nk) {
            stage(kt + 2, (kt + 2) % 3);                      // 12 in flight
            asm volatile("s_waitcnt vmcnt(8)" ::: "memory");  // tile-kt retired
        } else if (kt + 1 < nk) {
            asm volatile("s_waitcnt vmcnt(4)" ::: "memory");
        } else {
            asm volatile("s_waitcnt vmcnt(0)" ::: "memory");
        }
        __builtin_amdgcn_s_barrier();        // all waves' tile-kt loads landed
        __builtin_amdgcn_sched_barrier(0);   // no ds_read hoisting above barrier
        __builtin_amdgcn_s_setprio(1);
        compute(kt % 3);
        __builtin_amdgcn_s_setprio(0);
        __builtin_amdgcn_sched_barrier(0);
        __builtin_amdgcn_s_barrier();        // all reads of buf kt%3 done before reuse
    }

    // C/D frag layout: col = lane&15, row = (lane>>4)*4 + j   [guide-verified]
    const int gr0 = bm * BM + wr * 64 + kh * 4;
    const int gc0 = bn * BN + wc * 64 + col0;
    if (mode == 0) {
        bf16_t* C = (bf16_t*)Cout;
#pragma unroll
        for (int mi = 0; mi < 4; ++mi)
#pragma unroll
            for (int ni = 0; ni < 4; ++ni) {
                const int c = gc0 + ni * 16;
                const float bv = bias ? bias[c] : 0.f;
#pragma unroll
                for (int j = 0; j < 4; ++j) {
                    const int r = gr0 + mi * 16 + j;
                    C[(size_t)r * N + c] = (bf16_t)(acc[mi][ni][j] + bv);
                }
            }
    } else {
        float* C = (float*)Cout;
#pragma unroll
        for (int mi = 0; mi < 4; ++mi)
#pragma unroll
            for (int ni = 0; ni < 4; ++ni) {
                const int c = gc0 + ni * 16;
                const float bv = bias[c];
#pragma unroll
                for (int j = 0; j < 4; ++j) {
                    const int r = gr0 + mi * 16 + j;
                    float v = acc[mi][ni][j] + bv;
                    C[(size_t)r * N + c] = v / (1.f + __expf(-v));
                }
            }
    }
}

__global__ void cast8_kernel(const float* __restrict__ in, bf16_t* __restrict__ out, int n8) {
    const int i = blockIdx.x * blockDim.x + threadIdx.x;
    if (i >= n8) return;
    const float4* p = (const float4*)in + (size_t)i * 2;
    float4 a = p[0], b = p[1];
    bf16x8 v;
    v[0] = (bf16_t)a.x; v[1] = (bf16_t)a.y; v[2] = (bf16_t)a.z; v[3] = (bf16_t)a.w;
    v[4] = (bf16_t)b.x; v[5] = (bf16_t)b.y; v[6] = (bf16_t)b.z; v[7] = (bf16_t)b.w;
    *(bf16x8*)(out + (size_t)i * 8) = v;
}

// out[c*R + r] = in[r*C + c]   (in: R x C, out: C x R), cast to bf16
__global__ void transpose_cast_kernel(const float* __restrict__ in, bf16_t* __restrict__ out,
                                      int R, int C) {
    const int idx = blockIdx.x * blockDim.x + threadIdx.x;
    if (idx >= R * C) return;
    const int c = idx / R;
    const int r = idx - c * R;
    out[idx] = (bf16_t)in[(size_t)r * C + c];
}

// u[t] = sum_i v[i] * W[i][t]
__global__ void vecmat_kernel(const float* __restrict__ v, const float* __restrict__ W,
                              float* __restrict__ out) {
    const int t = blockIdx.x * blockDim.x + threadIdx.x;
    if (t >= 512) return;
    float s = 0.f;
    for (int i = 0; i < 512; ++i) s += v[i] * W[i * 512 + t];
    out[t] = s;
}

// per node: s = g.W3 ; chi_bo = chi*s ; A3[n, l*512+f] = c_l * g[f]^2
__global__ __launch_bounds__(256)
void mid_kernel(const bf16_t* __restrict__ G, const float* __restrict__ chi,
                const float* __restrict__ W3, float* __restrict__ chbo,
                bf16_t* __restrict__ A3)
{
    const int node = blockIdx.x * 4 + (threadIdx.x >> 6);
    const int lane = threadIdx.x & 63;

    const bf16x8 gv = *(const bf16x8*)(G + (size_t)node * 512 + lane * 8);
    float g[8];
#pragma unroll
    for (int j = 0; j < 8; ++j) g[j] = (float)gv[j];

    float s = 0.f;
    const float* w = W3 + lane * 8;
#pragma unroll
    for (int j = 0; j < 8; ++j) s += g[j] * w[j];
#pragma unroll
    for (int off = 32; off > 0; off >>= 1) s += __shfl_xor(s, off, 64);

    const float* ch = chi + (size_t)node * 15;
    float c0 = 0.f, c1 = 0.f, c2 = 0.f;
#pragma unroll
    for (int m = 0; m < 3; ++m)  c0 += ch[m] * ch[m];
#pragma unroll
    for (int m = 3; m < 8; ++m)  c1 += ch[m] * ch[m];
#pragma unroll
    for (int m = 8; m < 15; ++m) c2 += ch[m] * ch[m];

    if (lane < 15) chbo[(size_t)node * 15 + lane] = ch[lane] * s;

    const float cl[3] = {c0, c1, c2};
    bf16_t* arow = A3 + (size_t)node * 1536 + lane * 8;
#pragma unroll
    for (int l = 0; l < 3; ++l) {
        bf16x8 o;
#pragma unroll
        for (int j = 0; j < 8; ++j) o[j] = (bf16_t)(cl[l] * g[j] * g[j]);
        *(bf16x8*)(arow + l * 512) = o;
    }
}

extern "C" void kernel_launch(void* const* d_in, const int* in_sizes, int n_in,
                              void* d_out, int out_size, void* d_ws, size_t ws_size,
                              hipStream_t stream)
{
    const float* x   = (const float*)d_in[0];
    const float* chi = (const float*)d_in[1];
    // d_in[2] = z_one_hot : unused by the reference computation
    const float* W1  = (const float*)d_in[3];
    const float* b1  = (const float*)d_in[4];
    const float* W2  = (const float*)d_in[5];
    const float* W3  = (const float*)d_in[6];
    const float* W4  = (const float*)d_in[7];
    const float* b4  = (const float*)d_in[8];

    char* ws = (char*)d_ws;
    bf16_t* W1b = (bf16_t*)(ws + 0);
    bf16_t* W2t = (bf16_t*)(ws + 524288);
    bf16_t* W4t = (bf16_t*)(ws + 1048576);
    bf16_t* Wct = (bf16_t*)(ws + 2621440);
    float*  bc  = (float*) (ws + 3145728);
    float*  u   = (float*) (ws + 3147776);
    bf16_t* Xb  = (bf16_t*)(ws + 3149824);
    bf16_t* A3  = (bf16_t*)(ws + 3149824);   // overlaps Xb (dead by then)

    float*  xbo  = (float*)d_out;                                // 24576*512 f32
    float*  chbo = (float*)d_out + (size_t)24576 * 512;          // 24576*15 f32
    bf16_t* Gb   = (bf16_t*)d_out;   // bf16 scratch inside chunk0 (dead before final GEMM)

    // prep: casts / transposes / fused bias  bc = (b1 @ W1) @ W2
    cast8_kernel<<<6144, 256, 0, stream>>>(x, Xb, 1572864);
    cast8_kernel<<<128, 256, 0, stream>>>(W1, W1b, 32768);
    transpose_cast_kernel<<<1024, 256, 0, stream>>>(W2, W2t, 512, 512);
    transpose_cast_kernel<<<3072, 256, 0, stream>>>(W4, W4t, 1536, 512);
    vecmat_kernel<<<2, 256, 0, stream>>>(b1, W1, u);
    vecmat_kernel<<<2, 256, 0, stream>>>(u, W2, bc);

    // Wct = (W1@W2)^T = W2^T @ W1^T :  C[j][i] = sum_t W2t[j][t] * W1[i][t]
    gemm_bt_kernel<<<dim3(4, 4), 256, 0, stream>>>(W2t, W1b, nullptr, Wct, 512, 512, 0);

    // G = x @ (W1@W2) + bc : C[n][j] = sum_k Xb[n][k] * Wct[j][k] + bc[j]  -> bf16
    gemm_bt_kernel<<<dim3(192, 4), 256, 0, stream>>>(Xb, Wct, bc, Gb, 512, 512, 0);

    // s, chi_bo, A3
    mid_kernel<<<6144, 256, 0, stream>>>(Gb, chi, W3, chbo, A3);

    // x_bo = silu(A3 @ W4 + b4) : C[n][j] = sum_k A3[n][k] * W4t[j][k]
    gemm_bt_kernel<<<dim3(192, 4), 256, 0, stream>>>(A3, W4t, b4, xbo, 512, 1536, 1);
}